// Round 5
// baseline (37.428 us; speedup 1.0000x reference)
//
#include <hip/hip_runtime.h>
#include <math.h>

// ---------------------------------------------------------------------------
// RISVQCLayer: angles = tanh(fused @ W^T + b) * pi  -> 4-qubit VQC -> (z+1)*pi
// B=65536, HID=256, R=16 runs (64 outputs/sample), fp32 in/out.
//
// R4: barrier-free single-wave blocks (4096 x 64 thr, 16 samples/wave).
//  - fused B-fragments loaded直接 from global (no LDS staging, no barriers).
//  - pre^T acc layout (R2-verified): lane (l15,l4) owns runs r=4cg+l4 whole,
//    so Phase A (tanh->sincos->a01/a23 factors) runs straight from acc regs.
//  - U-apply per run = ONE mfma_f32_16x16x32_f16 with A=[U_hi|U_lo] (exact
//    split-fp16 U), B=[se;se] (se fp16). Kills the 1024 scalar FMAs of R3.
//  - Z-expectation: signed sums + __shfl_xor(16/32) butterfly over l4 group.
// d_ws: [0,32K) Wf fp16 frags; [32K,48K) UA fp16 frags; [48K,64K) U fp32 tmp.
// ---------------------------------------------------------------------------

#define PI_F 3.14159265358979323846f

typedef _Float16 f16x4 __attribute__((ext_vector_type(4)));
typedef _Float16 f16x8 __attribute__((ext_vector_type(8)));
typedef float    f32x4 __attribute__((ext_vector_type(4)));

__device__ __forceinline__ void ry_gate(float st[16], float c, float s, int w) {
    const int m = 1 << (3 - w);
    #pragma unroll
    for (int i = 0; i < 16; ++i) {
        if (i & m) continue;
        float a = st[i];
        float b = st[i | m];
        st[i]     = c * a - s * b;
        st[i | m] = s * a + c * b;
    }
}

__device__ __forceinline__ void cnot_gate(float st[16], int cw, int tw) {
    const int cm = 1 << (3 - cw);
    const int tm = 1 << (3 - tw);
    #pragma unroll
    for (int i = 0; i < 16; ++i) {
        if ((i & cm) && !(i & tm)) {
            float tmp = st[i];
            st[i] = st[i | tm];
            st[i | tm] = tmp;
        }
    }
}

// prep: block0 -> U matrices then fp16 hi/lo A-fragments; block1 -> W frags.
__global__ void prep_kernel(const float* __restrict__ vw,
                            const float* __restrict__ W,
                            char* __restrict__ ws) {
    const int tid = threadIdx.x;   // 256
    if (blockIdx.x == 0) {
        float* Ut = (float*)(ws + 49152);          // fp32 U[r][i][j]
        {   // phase 1: thread (r, j) computes column j of U_r
            const int r = tid >> 4, j = tid & 15;
            const float* wr = vw + r * 16;
            float cs[16], sn[16];
            #pragma unroll
            for (int i = 0; i < 16; ++i) {
                float h = wr[i] * 0.5f;
                cs[i] = __cosf(h);
                sn[i] = __sinf(h);
            }
            float st[16];
            #pragma unroll
            for (int i = 0; i < 16; ++i) st[i] = 0.f;
            st[j] = 1.f;
            #pragma unroll
            for (int w = 0; w < 4; ++w) ry_gate(st, cs[w], sn[w], w);
            cnot_gate(st, 0, 1);
            cnot_gate(st, 2, 3);
            #pragma unroll
            for (int w = 0; w < 4; ++w) ry_gate(st, cs[4 + w], sn[4 + w], w);
            cnot_gate(st, 1, 2);
            cnot_gate(st, 3, 0);
            #pragma unroll
            for (int w = 0; w < 4; ++w) ry_gate(st, cs[8 + w], sn[8 + w], w);
            cnot_gate(st, 0, 1);
            cnot_gate(st, 1, 2);
            cnot_gate(st, 2, 3);
            cnot_gate(st, 3, 0);
            #pragma unroll
            for (int w = 0; w < 4; ++w) ry_gate(st, cs[12 + w], sn[12 + w], w);
            #pragma unroll
            for (int i = 0; i < 16; ++i) Ut[r * 256 + i * 16 + j] = st[i];
        }
        __syncthreads();
        {   // phase 2: UA[r][lane] = 8 fp16: k<16 -> hi(U[l15][k]),
            //                         k>=16 -> lo(U[l15][k-16])
            _Float16* UA = (_Float16*)(ws + 32768);
            #pragma unroll
            for (int t = 0; t < 4; ++t) {
                int f = t * 256 + tid;             // 0..1023
                int r = f >> 6, lane = f & 63;
                int l15 = lane & 15, l4 = lane >> 4;
                const float* urow = Ut + r * 256 + l15 * 16;
                f16x8 h;
                #pragma unroll
                for (int e = 0; e < 8; ++e) {
                    int kl = 8 * l4 + e;
                    if (kl < 16) {
                        h[e] = (_Float16)urow[kl];
                    } else {
                        float u = urow[kl - 16];
                        _Float16 hi = (_Float16)u;
                        h[e] = (_Float16)(u - (float)hi);
                    }
                }
                *(f16x8*)(UA + f * 8) = h;
            }
        }
    } else {
        // W fragments (R3-verified layout): row=cg*16+l15, k=(kk*4+l4)*8+e
        _Float16* Wh = (_Float16*)ws;
        #pragma unroll
        for (int t = 0; t < 8; ++t) {
            int f  = tid * 8 + t;            // fragment id 0..2047
            int cg = f >> 9;
            int kk = (f >> 6) & 7;
            int l  = f & 63;
            int row = cg * 16 + (l & 15);
            int k0  = (kk * 4 + (l >> 4)) * 8;
            const float* src = W + row * 256 + k0;
            f16x8 h;
            #pragma unroll
            for (int e = 0; e < 8; ++e) h[e] = (_Float16)src[e];
            *(f16x8*)(Wh + f * 8) = h;
        }
    }
}

__global__ __launch_bounds__(64, 4) void vqc_main_kernel(
        const float* __restrict__ fused,   // (65536, 256)
        const char* __restrict__ ws,       // Wf + UA fragments
        const float* __restrict__ bp,      // (64,)
        float* __restrict__ out) {         // (65536, 64)
    __shared__ float tab[16 * 16 * 9];     // [run][sample][a01[4],a23[4],pad]

    const int lane = threadIdx.x;          // 64
    const int l15  = lane & 15;
    const int l4   = lane >> 4;
    const size_t s0 = (size_t)blockIdx.x * 16;
    const float* frow = fused + (s0 + l15) * 256;

    // ---- B fragments of fused, direct from global ----
    f16x8 bf[8];
    #pragma unroll
    for (int kk = 0; kk < 8; ++kk) {
        float4 u0 = *(const float4*)(frow + kk * 32 + l4 * 8);
        float4 u1 = *(const float4*)(frow + kk * 32 + l4 * 8 + 4);
        f16x8 h;
        h[0] = (_Float16)u0.x; h[1] = (_Float16)u0.y;
        h[2] = (_Float16)u0.z; h[3] = (_Float16)u0.w;
        h[4] = (_Float16)u1.x; h[5] = (_Float16)u1.y;
        h[6] = (_Float16)u1.z; h[7] = (_Float16)u1.w;
        bf[kk] = h;
    }

    // ---- MFMA: pre^T = W x fused^T  (acc[cg][j] = angle 16cg+4l4+j of l15) --
    const f16x8* Wf = (const f16x8*)ws;
    f32x4 acc[4] = {};
    #pragma unroll
    for (int kk = 0; kk < 8; ++kk) {
        #pragma unroll
        for (int cg = 0; cg < 4; ++cg) {
            f16x8 af = Wf[(cg * 8 + kk) * 64 + lane];
            acc[cg] = __builtin_amdgcn_mfma_f32_16x16x32_f16(af, bf[kk], acc[cg], 0, 0, 0);
        }
    }

    // ---- Phase A: lane owns runs r=4cg+l4; build a01/a23 factor table ----
    #pragma unroll
    for (int cg = 0; cg < 4; ++cg) {
        const int r = cg * 4 + l4;
        float4 bb = *(const float4*)(bp + 16 * cg + 4 * l4);
        float bias[4] = {bb.x, bb.y, bb.z, bb.w};
        float cc[4], ssn[4];
        #pragma unroll
        for (int w = 0; w < 4; ++w) {
            float pre = acc[cg][w] + bias[w];
            float e   = __expf(2.f * pre);
            float th  = __fdividef(e - 1.f, e + 1.f);   // tanh(pre)
            float hh  = th * (0.5f * PI_F);             // theta/2
            __sincosf(hh, &ssn[w], &cc[w]);
        }
        float* slot = tab + (r * 16 + l15) * 9;
        slot[0] = cc[0] * cc[1];  slot[1] = cc[0] * ssn[1];
        slot[2] = ssn[0] * cc[1]; slot[3] = ssn[0] * ssn[1];
        slot[4] = cc[2] * cc[3];  slot[5] = cc[2] * ssn[3];
        slot[6] = ssn[2] * cc[3]; slot[7] = ssn[2] * ssn[3];
    }

    // ---- Phase B: per run, o = (U_hi+U_lo)*se via ONE mfma (K=32) ----
    const float sg0 = (l4 < 2) ? 1.f : -1.f;        // sign of bit3 of state
    const float sg1 = ((l4 & 1) == 0) ? 1.f : -1.f; // sign of bit2
    const int   h8  = (l4 & 1) * 2;                 // a01 base for se half
    const f16x8* UA = (const f16x8*)(ws + 32768);

    #pragma unroll 4
    for (int r = 0; r < 16; ++r) {
        const float* t = tab + (r * 16 + l15) * 9;
        float a01a = t[h8], a01b = t[h8 + 1];
        float b0 = t[4], b1 = t[5], b2 = t[6], b3 = t[7];
        f16x8 se;
        se[0] = (_Float16)(a01a * b0); se[1] = (_Float16)(a01a * b1);
        se[2] = (_Float16)(a01a * b2); se[3] = (_Float16)(a01a * b3);
        se[4] = (_Float16)(a01b * b0); se[5] = (_Float16)(a01b * b1);
        se[6] = (_Float16)(a01b * b2); se[7] = (_Float16)(a01b * b3);

        f16x8 ua = UA[r * 64 + lane];
        f32x4 zero = {};
        f32x4 o = __builtin_amdgcn_mfma_f32_16x16x32_f16(ua, se, zero, 0, 0, 0);

        // lane holds states 4*l4+j of sample l15
        float p0 = o[0] * o[0], p1 = o[1] * o[1];
        float p2 = o[2] * o[2], p3 = o[3] * o[3];
        float S  = (p0 + p1) + (p2 + p3);
        float z0 = sg0 * S;
        float z1 = sg1 * S;
        float z2 = (p0 + p1) - (p2 + p3);
        float z3 = (p0 - p1) + (p2 - p3);
        z0 += __shfl_xor(z0, 16); z0 += __shfl_xor(z0, 32);
        z1 += __shfl_xor(z1, 16); z1 += __shfl_xor(z1, 32);
        z2 += __shfl_xor(z2, 16); z2 += __shfl_xor(z2, 32);
        z3 += __shfl_xor(z3, 16); z3 += __shfl_xor(z3, 32);

        if (l4 == (r & 3)) {
            float4 ov;
            ov.x = (z0 + 1.f) * PI_F;
            ov.y = (z1 + 1.f) * PI_F;
            ov.z = (z2 + 1.f) * PI_F;
            ov.w = (z3 + 1.f) * PI_F;
            *(float4*)(out + (s0 + l15) * 64 + 4 * r) = ov;
        }
    }
}

extern "C" void kernel_launch(void* const* d_in, const int* in_sizes, int n_in,
                              void* d_out, int out_size, void* d_ws, size_t ws_size,
                              hipStream_t stream) {
    const float* fused = (const float*)d_in[0];   // (65536, 256)
    const float* Wp    = (const float*)d_in[1];   // (64, 256)
    const float* bp    = (const float*)d_in[2];   // (64,)
    const float* vw    = (const float*)d_in[3];   // (16, 4, 4)
    float* out = (float*)d_out;                   // (65536, 64)
    char*  ws  = (char*)d_ws;                     // 64 KB used

    prep_kernel<<<2, 256, 0, stream>>>(vw, Wp, ws);

    const int B = 65536;
    vqc_main_kernel<<<B / 16, 64, 0, stream>>>(fused, ws, bp, out);
}